// Round 5
// baseline (2115.923 us; speedup 1.0000x reference)
//
#include <hip/hip_runtime.h>
#include <math.h>

#define IN_DIM 256
#define OUT_DIM 64
#define BROWS 256            // dst rows per bucket (LDS acc = 256*64*4 = 64 KB)
#define EPB 16               // edges per thread in pass-1 multisplit
#define P1_EDGES (256 * EPB) // 4096 edges per block
#define GEMM_BLOCKS 512      // 2 blocks/CU

// ---------------------------------------------------------------------------
// K1: integer degree histogram (norms need both degrees). 2 atomics/edge.
// ---------------------------------------------------------------------------
__global__ void deg_kernel(const int* __restrict__ src, const int* __restrict__ dst,
                           int* __restrict__ out_deg, int* __restrict__ in_deg,
                           int n_edges) {
    int e = blockIdx.x * blockDim.x + threadIdx.x;
    if (e < n_edges) {
        atomicAdd(&out_deg[src[e]], 1);
        atomicAdd(&in_deg[dst[e]], 1);
    }
}

// ---------------------------------------------------------------------------
// K2: bucket histogram over dst>>8. LDS-privatized, one global add per
// (block,bucket).
// ---------------------------------------------------------------------------
__global__ void __launch_bounds__(256) hist_kernel(
        const int* __restrict__ dst, int* __restrict__ bucket_hist,
        int n_edges, int nb) {
    __shared__ int lh[512];
    for (int i = threadIdx.x; i < nb; i += 256) lh[i] = 0;
    __syncthreads();
    const int base = blockIdx.x * P1_EDGES;
    #pragma unroll
    for (int i = 0; i < EPB; ++i) {
        int e = base + i * 256 + threadIdx.x;
        if (e < n_edges) atomicAdd(&lh[dst[e] >> 8], 1);
    }
    __syncthreads();
    for (int i = threadIdx.x; i < nb; i += 256)
        if (lh[i]) atomicAdd(&bucket_hist[i], lh[i]);
}

// ---------------------------------------------------------------------------
// K3: exclusive scan of bucket counts (tiny; nb ~ 391).
// ---------------------------------------------------------------------------
__global__ void bucket_scan_kernel(const int* __restrict__ hist,
                                   int* __restrict__ base, int* __restrict__ cursor,
                                   int nb) {
    if (threadIdx.x == 0 && blockIdx.x == 0) {
        int acc = 0;
        for (int i = 0; i < nb; ++i) {
            base[i] = acc;
            cursor[i] = acc;
            acc += hist[i];
        }
        base[nb] = acc;
    }
}

// ---------------------------------------------------------------------------
// K4: pass-1 multisplit. Each block: count its 4096 edges per bucket in LDS,
// reserve contiguous slots with ONE global atomic per (block,bucket), then
// write packed (src<<8 | dst&255) into the reserved segments (~80B each ->
// good line utilization, no 64B-per-4B write amplification).
// ---------------------------------------------------------------------------
__global__ void __launch_bounds__(256) scatter_pairs_kernel(
        const int* __restrict__ src, const int* __restrict__ dst,
        int* __restrict__ cursor, unsigned* __restrict__ pairs,
        int n_edges, int nb) {
    __shared__ int lh[512];     // per-bucket local count, then local cursor
    __shared__ int lbase[512];  // per-bucket reserved global base
    for (int i = threadIdx.x; i < nb; i += 256) lh[i] = 0;
    __syncthreads();

    const int base = blockIdx.x * P1_EDGES;
    int s[EPB], d[EPB];
    #pragma unroll
    for (int i = 0; i < EPB; ++i) {
        int e = base + i * 256 + threadIdx.x;
        if (e < n_edges) {
            s[i] = src[e];
            d[i] = dst[e];
            atomicAdd(&lh[d[i] >> 8], 1);
        } else {
            s[i] = -1; d[i] = 0;
        }
    }
    __syncthreads();
    for (int i = threadIdx.x; i < nb; i += 256) {
        int c = lh[i];
        lbase[i] = c ? atomicAdd(&cursor[i], c) : 0;
        lh[i] = 0;  // reuse as local cursor
    }
    __syncthreads();
    #pragma unroll
    for (int i = 0; i < EPB; ++i) {
        if (s[i] >= 0) {
            int bkt = d[i] >> 8;
            int pos = lbase[bkt] + atomicAdd(&lh[bkt], 1);
            pairs[pos] = ((unsigned)s[i] << 8) | (unsigned)(d[i] & 255);
        }
    }
}

// ---------------------------------------------------------------------------
// K5: m[row] = (h[row] @ W) * rsqrt(max(out_deg,1)). Persistent, W in LDS
// once per block, 8 rows/wave, wave-uniform row base.
// ---------------------------------------------------------------------------
__global__ void __launch_bounds__(256) gemm_kernel(
        const float* __restrict__ h, const float* __restrict__ W,
        const int* __restrict__ out_deg, float* __restrict__ m, int n_nodes) {
    __shared__ float Wl[IN_DIM * OUT_DIM];  // 64 KB
    {
        const float4* W4 = (const float4*)W;
        float4* Wl4 = (float4*)Wl;
        #pragma unroll
        for (int i = 0; i < (IN_DIM * OUT_DIM / 4) / 256; ++i)
            Wl4[threadIdx.x + i * 256] = W4[threadIdx.x + i * 256];
    }
    __syncthreads();

    const int lane = threadIdx.x & 63;
    const int waveId = (blockIdx.x << 2) | (threadIdx.x >> 6);
    const int nWaves = gridDim.x << 2;

    const int nTiles = n_nodes >> 3;
    for (int tile = waveId; tile < nTiles; tile += nWaves) {
        const int rowBase = __builtin_amdgcn_readfirstlane(tile << 3);
        const float4* __restrict__ hp = (const float4*)(h + (size_t)rowBase * IN_DIM);
        float acc[8] = {0.f, 0.f, 0.f, 0.f, 0.f, 0.f, 0.f, 0.f};

        #pragma unroll 2
        for (int k4 = 0; k4 < IN_DIM / 4; ++k4) {
            float w0 = Wl[(k4 * 4 + 0) * OUT_DIM + lane];
            float w1 = Wl[(k4 * 4 + 1) * OUT_DIM + lane];
            float w2 = Wl[(k4 * 4 + 2) * OUT_DIM + lane];
            float w3 = Wl[(k4 * 4 + 3) * OUT_DIM + lane];
            #pragma unroll
            for (int r = 0; r < 8; ++r) {
                float4 hv = hp[r * (IN_DIM / 4) + k4];
                acc[r] += hv.x * w0 + hv.y * w1 + hv.z * w2 + hv.w * w3;
            }
        }

        #pragma unroll
        for (int r = 0; r < 8; ++r) {
            float nr = rsqrtf(fmaxf((float)out_deg[rowBase + r], 1.0f));
            m[(size_t)(rowBase + r) * OUT_DIM + lane] = acc[r] * nr;
        }
    }

    for (int r = nTiles * 8 + waveId; r < n_nodes; r += nWaves) {
        float acc = 0.f;
        for (int k = 0; k < IN_DIM; ++k)
            acc += h[(size_t)r * IN_DIM + k] * Wl[k * OUT_DIM + lane];
        float nr = rsqrtf(fmaxf((float)out_deg[r], 1.0f));
        m[(size_t)r * OUT_DIM + lane] = acc * nr;
    }
}

// ---------------------------------------------------------------------------
// K6: pass-2 fused SpMM + epilogue. One block per bucket; 64 KB LDS
// accumulator over the bucket's 256 dst rows. Waves stream packed edges
// (shfl broadcast), gather m[src] rows (256B coalesced, 8 in flight),
// ds_add into LDS, then fused norm_dst + bias + log_softmax writes each
// output row exactly once.
// ---------------------------------------------------------------------------
__global__ void __launch_bounds__(256) spmm_acc_kernel(
        const unsigned* __restrict__ pairs, const int* __restrict__ bucket_base,
        const float* __restrict__ m, const int* __restrict__ in_deg,
        const float* __restrict__ bias, float* __restrict__ out, int n_nodes) {
    __shared__ float acc[BROWS * OUT_DIM];  // 64 KB
    const int lane = threadIdx.x & 63;
    const int wave = threadIdx.x >> 6;
    const int bucket = blockIdx.x;
    const int rowBase = bucket * BROWS;
    const int nrows = min(BROWS, n_nodes - rowBase);

    {
        float4* a4 = (float4*)acc;
        #pragma unroll
        for (int i = 0; i < (BROWS * OUT_DIM / 4) / 256; ++i)
            a4[threadIdx.x + i * 256] = make_float4(0.f, 0.f, 0.f, 0.f);
    }
    __syncthreads();

    const int beg = bucket_base[bucket];
    const int end = bucket_base[bucket + 1];

    for (int cb = beg + wave * 64; cb < end; cb += 4 * 64) {
        const int cnt = min(64, end - cb);
        unsigned pk = (lane < cnt) ? pairs[cb + lane] : 0u;
        int i = 0;
        for (; i + 8 <= cnt; i += 8) {
            unsigned u0 = __shfl(pk, i + 0, 64);
            unsigned u1 = __shfl(pk, i + 1, 64);
            unsigned u2 = __shfl(pk, i + 2, 64);
            unsigned u3 = __shfl(pk, i + 3, 64);
            unsigned u4 = __shfl(pk, i + 4, 64);
            unsigned u5 = __shfl(pk, i + 5, 64);
            unsigned u6 = __shfl(pk, i + 6, 64);
            unsigned u7 = __shfl(pk, i + 7, 64);
            float v0 = m[(size_t)(u0 >> 8) * OUT_DIM + lane];
            float v1 = m[(size_t)(u1 >> 8) * OUT_DIM + lane];
            float v2 = m[(size_t)(u2 >> 8) * OUT_DIM + lane];
            float v3 = m[(size_t)(u3 >> 8) * OUT_DIM + lane];
            float v4 = m[(size_t)(u4 >> 8) * OUT_DIM + lane];
            float v5 = m[(size_t)(u5 >> 8) * OUT_DIM + lane];
            float v6 = m[(size_t)(u6 >> 8) * OUT_DIM + lane];
            float v7 = m[(size_t)(u7 >> 8) * OUT_DIM + lane];
            atomicAdd(&acc[(u0 & 255u) * OUT_DIM + lane], v0);
            atomicAdd(&acc[(u1 & 255u) * OUT_DIM + lane], v1);
            atomicAdd(&acc[(u2 & 255u) * OUT_DIM + lane], v2);
            atomicAdd(&acc[(u3 & 255u) * OUT_DIM + lane], v3);
            atomicAdd(&acc[(u4 & 255u) * OUT_DIM + lane], v4);
            atomicAdd(&acc[(u5 & 255u) * OUT_DIM + lane], v5);
            atomicAdd(&acc[(u6 & 255u) * OUT_DIM + lane], v6);
            atomicAdd(&acc[(u7 & 255u) * OUT_DIM + lane], v7);
        }
        for (; i < cnt; ++i) {
            unsigned u = __shfl(pk, i, 64);
            float v = m[(size_t)(u >> 8) * OUT_DIM + lane];
            atomicAdd(&acc[(u & 255u) * OUT_DIM + lane], v);
        }
    }
    __syncthreads();

    const float bl = bias[lane];
    for (int r = wave; r < nrows; r += 4) {
        float nd = rsqrtf(fmaxf((float)in_deg[rowBase + r], 1.0f));
        float x = acc[r * OUT_DIM + lane] * nd + bl;
        float mx = x;
        #pragma unroll
        for (int o = 32; o > 0; o >>= 1) mx = fmaxf(mx, __shfl_xor(mx, o, 64));
        float ex = expf(x - mx);
        float ss = ex;
        #pragma unroll
        for (int o = 32; o > 0; o >>= 1) ss += __shfl_xor(ss, o, 64);
        out[(size_t)(rowBase + r) * OUT_DIM + lane] = x - mx - logf(ss);
    }
}

// ---------------------------------------------------------------------------
static inline size_t align16(size_t x) { return (x + 15) & ~(size_t)15; }

extern "C" void kernel_launch(void* const* d_in, const int* in_sizes, int n_in,
                              void* d_out, int out_size, void* d_ws, size_t ws_size,
                              hipStream_t stream) {
    const float* h = (const float*)d_in[0];
    const float* W = (const float*)d_in[1];
    const float* b = (const float*)d_in[2];
    const int* edges = (const int*)d_in[3];

    const int out_dim = in_sizes[2];            // 64
    const int in_dim  = in_sizes[1] / out_dim;  // 256
    const int n_nodes = in_sizes[0] / in_dim;   // 100000
    const int n_edges = in_sizes[3] / 2;        // 3200000

    const int* src = edges;
    const int* dst = edges + n_edges;

    float* out = (float*)d_out;

    const int nb = (n_nodes + BROWS - 1) / BROWS;  // 391 buckets

    // workspace carve-up
    char* ws = (char*)d_ws;
    size_t off = 0;
    int* in_deg        = (int*)(ws + off); off = align16(off + (size_t)n_nodes * 4);
    int* out_deg       = (int*)(ws + off); off = align16(off + (size_t)n_nodes * 4);
    int* bucket_hist   = (int*)(ws + off); off = align16(off + (size_t)nb * 4);
    int* bucket_base   = (int*)(ws + off); off = align16(off + (size_t)(nb + 1) * 4);
    int* bucket_cursor = (int*)(ws + off); off = align16(off + (size_t)nb * 4);
    float* m           = (float*)(ws + off); off = align16(off + (size_t)n_nodes * OUT_DIM * 4);
    unsigned* pairs    = (unsigned*)(ws + off); off = align16(off + (size_t)n_edges * 4);

    (void)hipMemsetAsync(in_deg, 0, (size_t)n_nodes * sizeof(int), stream);
    (void)hipMemsetAsync(out_deg, 0, (size_t)n_nodes * sizeof(int), stream);
    (void)hipMemsetAsync(bucket_hist, 0, (size_t)nb * sizeof(int), stream);

    const int p1_blocks = (n_edges + P1_EDGES - 1) / P1_EDGES;

    deg_kernel<<<(n_edges + 255) / 256, 256, 0, stream>>>(src, dst, out_deg, in_deg, n_edges);

    hist_kernel<<<p1_blocks, 256, 0, stream>>>(dst, bucket_hist, n_edges, nb);
    bucket_scan_kernel<<<1, 64, 0, stream>>>(bucket_hist, bucket_base, bucket_cursor, nb);
    scatter_pairs_kernel<<<p1_blocks, 256, 0, stream>>>(src, dst, bucket_cursor, pairs, n_edges, nb);

    gemm_kernel<<<GEMM_BLOCKS, 256, 0, stream>>>(h, W, out_deg, m, n_nodes);

    spmm_acc_kernel<<<nb, 256, 0, stream>>>(pairs, bucket_base, m, in_deg, b, out, n_nodes);
}

// Round 6
// 731.207 us; speedup vs baseline: 2.8937x; 2.8937x over previous
//
#include <hip/hip_runtime.h>
#include <math.h>

#define IN_DIM 256
#define OUT_DIM 64
#define BROWS 256            // dst rows per bucket
#define EPB 16               // edges per thread in pass-1 multisplit
#define P1_EDGES (256 * EPB) // 4096 edges per block
#define GEMM_BLOCKS 512      // 2 blocks/CU

// ---------------------------------------------------------------------------
// K1: out-degree histogram only (in-degree comes free from CSR row extents).
// ---------------------------------------------------------------------------
__global__ void deg_kernel(const int* __restrict__ src,
                           int* __restrict__ out_deg, int n_edges) {
    int e = blockIdx.x * blockDim.x + threadIdx.x;
    if (e < n_edges) atomicAdd(&out_deg[src[e]], 1);
}

// ---------------------------------------------------------------------------
// K2: bucket histogram over dst>>8. LDS-privatized.
// ---------------------------------------------------------------------------
__global__ void __launch_bounds__(256) hist_kernel(
        const int* __restrict__ dst, int* __restrict__ bucket_hist,
        int n_edges, int nb) {
    __shared__ int lh[512];
    for (int i = threadIdx.x; i < nb; i += 256) lh[i] = 0;
    __syncthreads();
    const int base = blockIdx.x * P1_EDGES;
    #pragma unroll
    for (int i = 0; i < EPB; ++i) {
        int e = base + i * 256 + threadIdx.x;
        if (e < n_edges) atomicAdd(&lh[dst[e] >> 8], 1);
    }
    __syncthreads();
    for (int i = threadIdx.x; i < nb; i += 256)
        if (lh[i]) atomicAdd(&bucket_hist[i], lh[i]);
}

// ---------------------------------------------------------------------------
// K3: exclusive scan of bucket counts (tiny; nb ~ 391). Also writes
// row_start[n_nodes] = n_edges.
// ---------------------------------------------------------------------------
__global__ void bucket_scan_kernel(const int* __restrict__ hist,
                                   int* __restrict__ base, int* __restrict__ cursor,
                                   int* __restrict__ row_start,
                                   int nb, int n_nodes) {
    if (threadIdx.x == 0 && blockIdx.x == 0) {
        int acc = 0;
        for (int i = 0; i < nb; ++i) {
            base[i] = acc;
            cursor[i] = acc;
            acc += hist[i];
        }
        base[nb] = acc;
        row_start[n_nodes] = acc;
    }
}

// ---------------------------------------------------------------------------
// K4: pass-1 multisplit. Block-local LDS counts -> one global atomic
// reservation per (block,bucket) -> packed (src<<8 | dst&255) written into
// per-bucket segments (~40B each; no 64B-line-per-4B write amplification).
// ---------------------------------------------------------------------------
__global__ void __launch_bounds__(256) scatter_pairs_kernel(
        const int* __restrict__ src, const int* __restrict__ dst,
        int* __restrict__ cursor, unsigned* __restrict__ pairs,
        int n_edges, int nb) {
    __shared__ int lh[512];     // per-bucket local count, then local cursor
    __shared__ int lbase[512];  // per-bucket reserved global base
    for (int i = threadIdx.x; i < nb; i += 256) lh[i] = 0;
    __syncthreads();

    const int base = blockIdx.x * P1_EDGES;
    int s[EPB], d[EPB];
    #pragma unroll
    for (int i = 0; i < EPB; ++i) {
        int e = base + i * 256 + threadIdx.x;
        if (e < n_edges) {
            s[i] = src[e];
            d[i] = dst[e];
            atomicAdd(&lh[d[i] >> 8], 1);
        } else {
            s[i] = -1; d[i] = 0;
        }
    }
    __syncthreads();
    for (int i = threadIdx.x; i < nb; i += 256) {
        int c = lh[i];
        lbase[i] = c ? atomicAdd(&cursor[i], c) : 0;
        lh[i] = 0;  // reuse as local cursor
    }
    __syncthreads();
    #pragma unroll
    for (int i = 0; i < EPB; ++i) {
        if (s[i] >= 0) {
            int bkt = d[i] >> 8;
            int pos = lbase[bkt] + atomicAdd(&lh[bkt], 1);
            pairs[pos] = ((unsigned)s[i] << 8) | (unsigned)(d[i] & 255);
        }
    }
}

// ---------------------------------------------------------------------------
// K5: bucket -> exact CSR. One block per bucket: LDS histogram of dst&255,
// block scan -> row_start, then scatter src into csr_src. All scatter writes
// land in this bucket's ~32 KB contiguous window -> L2 absorbs them.
// ---------------------------------------------------------------------------
__global__ void __launch_bounds__(256) bucket2csr_kernel(
        const unsigned* __restrict__ pairs, const int* __restrict__ bucket_base,
        int* __restrict__ row_start, int* __restrict__ csr_src, int n_nodes) {
    __shared__ int cnt[BROWS];
    __shared__ int scan[BROWS];
    const int b = blockIdx.x;
    const int beg = bucket_base[b];
    const int end = bucket_base[b + 1];
    const int rowBase = b * BROWS;

    cnt[threadIdx.x] = 0;
    __syncthreads();
    for (int i = beg + threadIdx.x; i < end; i += 256)
        atomicAdd(&cnt[pairs[i] & 255u], 1);
    __syncthreads();

    // inclusive block scan (Hillis-Steele over 256 elements)
    int v = cnt[threadIdx.x];
    scan[threadIdx.x] = v;
    __syncthreads();
    #pragma unroll
    for (int dstep = 1; dstep < 256; dstep <<= 1) {
        int t = (threadIdx.x >= dstep) ? scan[threadIdx.x - dstep] : 0;
        __syncthreads();
        scan[threadIdx.x] += t;
        __syncthreads();
    }
    const int excl = scan[threadIdx.x] - v;

    const int row = rowBase + threadIdx.x;
    if (row < n_nodes) row_start[row] = beg + excl;
    cnt[threadIdx.x] = beg + excl;  // reuse as cursor
    __syncthreads();

    for (int i = beg + threadIdx.x; i < end; i += 256) {
        unsigned p = pairs[i];
        int pos = atomicAdd(&cnt[p & 255u], 1);
        csr_src[pos] = (int)(p >> 8);
    }
}

// ---------------------------------------------------------------------------
// K6: m[row] = (h[row] @ W) * rsqrt(max(out_deg,1)). Persistent, W in LDS
// once per block, 8 rows/wave, wave-uniform row base.
// ---------------------------------------------------------------------------
__global__ void __launch_bounds__(256) gemm_kernel(
        const float* __restrict__ h, const float* __restrict__ W,
        const int* __restrict__ out_deg, float* __restrict__ m, int n_nodes) {
    __shared__ float Wl[IN_DIM * OUT_DIM];  // 64 KB
    {
        const float4* W4 = (const float4*)W;
        float4* Wl4 = (float4*)Wl;
        #pragma unroll
        for (int i = 0; i < (IN_DIM * OUT_DIM / 4) / 256; ++i)
            Wl4[threadIdx.x + i * 256] = W4[threadIdx.x + i * 256];
    }
    __syncthreads();

    const int lane = threadIdx.x & 63;
    const int waveId = (blockIdx.x << 2) | (threadIdx.x >> 6);
    const int nWaves = gridDim.x << 2;

    const int nTiles = n_nodes >> 3;
    for (int tile = waveId; tile < nTiles; tile += nWaves) {
        const int rowBase = __builtin_amdgcn_readfirstlane(tile << 3);
        const float4* __restrict__ hp = (const float4*)(h + (size_t)rowBase * IN_DIM);
        float acc[8] = {0.f, 0.f, 0.f, 0.f, 0.f, 0.f, 0.f, 0.f};

        #pragma unroll 2
        for (int k4 = 0; k4 < IN_DIM / 4; ++k4) {
            float w0 = Wl[(k4 * 4 + 0) * OUT_DIM + lane];
            float w1 = Wl[(k4 * 4 + 1) * OUT_DIM + lane];
            float w2 = Wl[(k4 * 4 + 2) * OUT_DIM + lane];
            float w3 = Wl[(k4 * 4 + 3) * OUT_DIM + lane];
            #pragma unroll
            for (int r = 0; r < 8; ++r) {
                float4 hv = hp[r * (IN_DIM / 4) + k4];
                acc[r] += hv.x * w0 + hv.y * w1 + hv.z * w2 + hv.w * w3;
            }
        }

        #pragma unroll
        for (int r = 0; r < 8; ++r) {
            float nr = rsqrtf(fmaxf((float)out_deg[rowBase + r], 1.0f));
            m[(size_t)(rowBase + r) * OUT_DIM + lane] = acc[r] * nr;
        }
    }

    for (int r = nTiles * 8 + waveId; r < n_nodes; r += nWaves) {
        float acc = 0.f;
        for (int k = 0; k < IN_DIM; ++k)
            acc += h[(size_t)r * IN_DIM + k] * Wl[k * OUT_DIM + lane];
        float nr = rsqrtf(fmaxf((float)out_deg[r], 1.0f));
        m[(size_t)r * OUT_DIM + lane] = acc * nr;
    }
}

// ---------------------------------------------------------------------------
// K7: CSR gather per dst row + fused norm_dst + bias + log_softmax.
// One wave per row; 8 gathers in flight; in-degree = row extent.
// ---------------------------------------------------------------------------
__global__ void __launch_bounds__(256) gather_kernel(
        const int* __restrict__ row_start, const int* __restrict__ csr_src,
        const float* __restrict__ m, const float* __restrict__ b,
        float* __restrict__ out, int n_nodes) {
    const int wave = threadIdx.x >> 6;
    const int lane = threadIdx.x & 63;
    const int row = blockIdx.x * 4 + wave;
    if (row >= n_nodes) return;

    const int beg = row_start[row];
    const int end = row_start[row + 1];

    float acc = 0.f;
    int i = beg;
    for (; i + 8 <= end; i += 8) {
        int s0 = csr_src[i + 0];
        int s1 = csr_src[i + 1];
        int s2 = csr_src[i + 2];
        int s3 = csr_src[i + 3];
        int s4 = csr_src[i + 4];
        int s5 = csr_src[i + 5];
        int s6 = csr_src[i + 6];
        int s7 = csr_src[i + 7];
        float v0 = m[(size_t)s0 * OUT_DIM + lane];
        float v1 = m[(size_t)s1 * OUT_DIM + lane];
        float v2 = m[(size_t)s2 * OUT_DIM + lane];
        float v3 = m[(size_t)s3 * OUT_DIM + lane];
        float v4 = m[(size_t)s4 * OUT_DIM + lane];
        float v5 = m[(size_t)s5 * OUT_DIM + lane];
        float v6 = m[(size_t)s6 * OUT_DIM + lane];
        float v7 = m[(size_t)s7 * OUT_DIM + lane];
        acc += v0 + v1 + v2 + v3 + v4 + v5 + v6 + v7;
    }
    for (; i < end; ++i) acc += m[(size_t)csr_src[i] * OUT_DIM + lane];

    float nd = rsqrtf(fmaxf((float)(end - beg), 1.0f));
    float x = acc * nd + b[lane];

    float mx = x;
    #pragma unroll
    for (int o = 32; o > 0; o >>= 1) mx = fmaxf(mx, __shfl_xor(mx, o, 64));
    float ex = expf(x - mx);
    float s = ex;
    #pragma unroll
    for (int o = 32; o > 0; o >>= 1) s += __shfl_xor(s, o, 64);
    out[(size_t)row * OUT_DIM + lane] = x - mx - logf(s);
}

// ---------------------------------------------------------------------------
static inline size_t align16(size_t x) { return (x + 15) & ~(size_t)15; }

extern "C" void kernel_launch(void* const* d_in, const int* in_sizes, int n_in,
                              void* d_out, int out_size, void* d_ws, size_t ws_size,
                              hipStream_t stream) {
    const float* h = (const float*)d_in[0];
    const float* W = (const float*)d_in[1];
    const float* b = (const float*)d_in[2];
    const int* edges = (const int*)d_in[3];

    const int out_dim = in_sizes[2];            // 64
    const int in_dim  = in_sizes[1] / out_dim;  // 256
    const int n_nodes = in_sizes[0] / in_dim;   // 100000
    const int n_edges = in_sizes[3] / 2;        // 3200000

    const int* src = edges;
    const int* dst = edges + n_edges;

    float* out = (float*)d_out;

    const int nb = (n_nodes + BROWS - 1) / BROWS;  // 391 buckets

    // workspace carve-up
    char* ws = (char*)d_ws;
    size_t off = 0;
    int* out_deg       = (int*)(ws + off); off = align16(off + (size_t)n_nodes * 4);
    int* row_start     = (int*)(ws + off); off = align16(off + (size_t)(n_nodes + 1) * 4);
    int* bucket_hist   = (int*)(ws + off); off = align16(off + (size_t)nb * 4);
    int* bucket_base   = (int*)(ws + off); off = align16(off + (size_t)(nb + 1) * 4);
    int* bucket_cursor = (int*)(ws + off); off = align16(off + (size_t)nb * 4);
    float* m           = (float*)(ws + off); off = align16(off + (size_t)n_nodes * OUT_DIM * 4);
    unsigned* pairs    = (unsigned*)(ws + off); off = align16(off + (size_t)n_edges * 4);
    int* csr_src       = (int*)(ws + off); off = align16(off + (size_t)n_edges * 4);

    (void)hipMemsetAsync(out_deg, 0, (size_t)n_nodes * sizeof(int), stream);
    (void)hipMemsetAsync(bucket_hist, 0, (size_t)nb * sizeof(int), stream);

    const int p1_blocks = (n_edges + P1_EDGES - 1) / P1_EDGES;

    deg_kernel<<<(n_edges + 255) / 256, 256, 0, stream>>>(src, out_deg, n_edges);

    hist_kernel<<<p1_blocks, 256, 0, stream>>>(dst, bucket_hist, n_edges, nb);
    bucket_scan_kernel<<<1, 64, 0, stream>>>(bucket_hist, bucket_base, bucket_cursor,
                                             row_start, nb, n_nodes);
    scatter_pairs_kernel<<<p1_blocks, 256, 0, stream>>>(src, dst, bucket_cursor, pairs, n_edges, nb);
    bucket2csr_kernel<<<nb, 256, 0, stream>>>(pairs, bucket_base, row_start, csr_src, n_nodes);

    gemm_kernel<<<GEMM_BLOCKS, 256, 0, stream>>>(h, W, out_deg, m, n_nodes);

    gather_kernel<<<(n_nodes + 3) / 4, 256, 0, stream>>>(row_start, csr_src, m, b, out, n_nodes);
}